// Round 17
// baseline (481.008 us; speedup 1.0000x reference)
//
#include <hip/hip_runtime.h>
#include <hip/hip_bf16.h>
#include <math.h>

// ---------------- problem constants ----------------
// x[4][8192][1024] fp32; Wqkv[1024][3072]; Wout[1024][1024]; bout[1024]
// ALL 4 batches in one pass (ws 512 MiB). ROWS = 32768.

typedef unsigned short ushort_t;
typedef __attribute__((ext_vector_type(8))) short s8v;   // 8 bf16 (4 VGPRs) MFMA A/B frag
typedef __attribute__((ext_vector_type(4))) float f32x4; // MFMA C/D frag

#define MFMA(a,b,c) __builtin_amdgcn_mfma_f32_16x16x32_bf16((a),(b),(c),0,0,0)

typedef __attribute__((address_space(3))) unsigned int as3_u32;
typedef __attribute__((address_space(1))) const unsigned int as1_u32c;

// async global -> LDS, 16B per lane. LDS dest = wave-uniform base + lane*16.
__device__ __forceinline__ void g2l16(const void* g, void* l) {
    __builtin_amdgcn_global_load_lds((as1_u32c*)g, (as3_u32*)l, 16, 0, 0);
}

__device__ __forceinline__ float bf2f(ushort_t u) {
    union { float f; unsigned v; } x; x.v = ((unsigned)u) << 16; return x.f;
}
__device__ __forceinline__ ushort_t f2bf(float f) {
    union { float f; unsigned v; } x; x.f = f;
    unsigned r = x.v + 0x7fffu + ((x.v >> 16) & 1u);   // RNE
    return (ushort_t)(r >> 16);
}
__device__ __forceinline__ float elu1(float t) { return t > 0.0f ? t + 1.0f : expf(t); }

// =====================================================================
// k_prep: ONE kernel for all preprocessing. Block-ID ranges:
//  [0,3072)        : WqkvT transpose tiles (32 k-tiles x 96 n-tiles)
//  [3072,4096)     : WoutT transpose tiles (32 x 32)
//  [4096,20480)    : x fp32 -> bf16 cast (16384 blocks x 2048 elems)
//  [20480,20512)   : zero kv+ksum (grid-stride float4)
// =====================================================================
__global__ __launch_bounds__(256) void k_prep(
    const float* __restrict__ x, const float* __restrict__ Wqkv,
    const float* __restrict__ Wout, ushort_t* __restrict__ xb,
    ushort_t* __restrict__ WqkvT, ushort_t* __restrict__ WoutT,
    float* __restrict__ zeroreg)
{
    const int bid = blockIdx.x, t = threadIdx.x;
    if (bid < 4096) {
        const float* W; ushort_t* WT; int K, N, idx;
        if (bid < 3072) { W = Wqkv; WT = WqkvT; K = 1024; N = 3072; idx = bid; }
        else            { W = Wout; WT = WoutT; K = 1024; N = 1024; idx = bid - 3072; }
        const int k0 = (idx & 31) * 32, n0 = (idx >> 5) * 32;
        __shared__ float s[32][33];
        const int kr = t >> 3, n4 = (t & 7) * 4;
        float4 v = *(const float4*)(W + (size_t)(k0 + kr) * N + n0 + n4);
        s[kr][n4 + 0] = v.x; s[kr][n4 + 1] = v.y; s[kr][n4 + 2] = v.z; s[kr][n4 + 3] = v.w;
        __syncthreads();
        const int nr = kr, k4 = n4;
        unsigned lo = (unsigned)f2bf(s[k4 + 0][nr]) | ((unsigned)f2bf(s[k4 + 1][nr]) << 16);
        unsigned hi = (unsigned)f2bf(s[k4 + 2][nr]) | ((unsigned)f2bf(s[k4 + 3][nr]) << 16);
        *(uint2*)(WT + (size_t)(n0 + nr) * K + k0 + k4) = make_uint2(lo, hi);
    } else if (bid < 20480) {
        const size_t i = (size_t)(bid - 4096) * 256 + t;     // < 4194304
        const float4* p = (const float4*)x;
        float4 a = p[i * 2], b = p[i * 2 + 1];
        uint4 o;
        o.x = (unsigned)f2bf(a.x) | ((unsigned)f2bf(a.y) << 16);
        o.y = (unsigned)f2bf(a.z) | ((unsigned)f2bf(a.w) << 16);
        o.z = (unsigned)f2bf(b.x) | ((unsigned)f2bf(b.y) << 16);
        o.w = (unsigned)f2bf(b.z) | ((unsigned)f2bf(b.w) << 16);
        *(uint4*)(xb + i * 8) = o;
    } else {
        float4* dst = (float4*)zeroreg;
        const float4 z4 = {0.f, 0.f, 0.f, 0.f};
        for (int i = (bid - 20480) * 256 + t; i < 263168; i += 8192)
            dst[i] = z4;
    }
}

// =====================================================================
// MFMA GEMM, m97 structure at 128x128 (guide: 912 TF for 2-barrier
// loops vs 792 at 256x256 -- tile choice is structure-dependent):
// BM=BN=128, BK=64, 4 waves (2x2, 64x64 each), 256 thr.
// Single-buffered 32 KB LDS -> 3-4 blocks/CU co-resident: one block's
// vmcnt(0)-drain overlaps another's MFMA burst (m114 inter-block
// overlap) -- the overlap a 1-block/CU 128KB config cannot get.
// Per K-tile: stage (8 gloads/wave); vmcnt(0); barrier; 2 k-halves x
// {8 ds_read_b128 + 16 MFMA}; barrier.
// XOR swizzle (R16, conflicts=0 measured): rows are 128B = 8 x 16B
// slots; stage-source slot (l&7)^lr; read elem ((l>>4)^(l&7))*8, ^32
// for kh1.
// __launch_bounds__(256,4): VGPR cap 128 (est ~105, no spill); 4
// waves/SIMD across blocks.
// 1-D grid + XCD-chunked bijective swizzle (T1), m-major.
// MODE 0: epilogue elu1 on cols<2048 -> qkv bf16 [M][3072]
// MODE 1: epilogue +bout -> out fp32 [M][1024]
// =====================================================================
template<int MODE>
__global__ __launch_bounds__(256, 4) void k_gemm(
    const ushort_t* __restrict__ A, const ushort_t* __restrict__ B,
    ushort_t* __restrict__ obf, const float* __restrict__ bout, float* __restrict__ of)
{
    constexpr int ASZ = 128 * 64;         // 8192 elems (16 KB) per matrix
    constexpr int NBN = (MODE == 0) ? 24 : 8;    // N blocks (3072 or 1024)
    constexpr int CH  = (256 * NBN) / 8;         // wgs per XCD chunk
    __shared__ ushort_t As[ASZ];          // 16 KB
    __shared__ ushort_t Bs[ASZ];          // 16 KB

    const int t = threadIdx.x, l = t & 63, w = t >> 6;   // 4 waves
    const int wr = w >> 1, wc = w & 1;                   // 2M x 2N
    // XCD-chunked bijective remap (hw XCD = orig % 8)
    const int orig = blockIdx.x;
    const int wg   = (orig & 7) * CH + (orig >> 3);
    const size_t m0 = (size_t)(wg / NBN) * 128;
    const size_t n0 = (size_t)(wg % NBN) * 128;

    f32x4 acc[4][4];
    const f32x4 z = {0.f, 0.f, 0.f, 0.f};
#pragma unroll
    for (int i = 0; i < 4; i++)
#pragma unroll
        for (int j = 0; j < 4; j++) acc[i][j] = z;

    // staging: 1KB chunk = 8 rows x 64 elems; wave w owns chunks 4w..4w+3
    // (rows 32w..32w+31). lane l -> row lr of chunk, swizzled source slot
    // (l&7)^lr.
    const int lr  = l >> 3;
    const int lco = ((l & 7) ^ lr) << 3;
    const ushort_t* gA = A + (m0 + (size_t)(32 * w) + lr) * 1024 + lco;
    const ushort_t* gB = B + (n0 + (size_t)(32 * w) + lr) * 1024 + lco;
    // fragment-read swizzle: LDS[r][slot s] = global[r][8*(s^(r&7))];
    // frag row r has r&7 == l&7; elem off = ((l>>4)^(l&7))*8, kh1: ^32.
    const int la15 = l & 15;
    const int exo  = (((l >> 4) ^ (l & 7)) << 3);

    for (int T = 0; T < 16; ++T) {
        const size_t k0 = (size_t)T * 64;
        // ---- stage tile T (single buffer)
#pragma unroll
        for (int i = 0; i < 4; i++) {
            g2l16(gA + (size_t)(8 * i) * 1024 + k0, &As[(w * 4 + i) * 512]);
            g2l16(gB + (size_t)(8 * i) * 1024 + k0, &Bs[(w * 4 + i) * 512]);
        }
        asm volatile("s_waitcnt vmcnt(0)" ::: "memory");
        __builtin_amdgcn_sched_barrier(0);
        __builtin_amdgcn_s_barrier();
        __builtin_amdgcn_sched_barrier(0);

        // ---- compute tile T: 2 k-halves x (8 ds_read_b128 + 16 MFMA)
#pragma unroll
        for (int kh = 0; kh < 2; kh++) {
            const int eo = (kh << 5) ^ exo;
            s8v af[4], bf[4];
#pragma unroll
            for (int nf = 0; nf < 4; nf++)
                bf[nf] = *(const s8v*)&Bs[(wc * 64 + nf * 16 + la15) * 64 + eo];
#pragma unroll
            for (int mf = 0; mf < 4; mf++)
                af[mf] = *(const s8v*)&As[(wr * 64 + mf * 16 + la15) * 64 + eo];
            __builtin_amdgcn_s_setprio(1);
#pragma unroll
            for (int mf = 0; mf < 4; mf++)
#pragma unroll
                for (int nf = 0; nf < 4; nf++)
                    acc[mf][nf] = MFMA(af[mf], bf[nf], acc[mf][nf]);
            __builtin_amdgcn_s_setprio(0);
        }
        __builtin_amdgcn_sched_barrier(0);
        __builtin_amdgcn_s_barrier();     // reads done before next stage
        __builtin_amdgcn_sched_barrier(0);
    }

    // ---------------- epilogue
    const int r4 = (l >> 4) * 4;
    if (MODE == 0) {
#pragma unroll
        for (int mf = 0; mf < 4; mf++)
#pragma unroll
            for (int nf = 0; nf < 4; nf++) {
                const size_t colb = n0 + wc * 64 + nf * 16;
                const bool feat = colb < 2048;
#pragma unroll
                for (int r = 0; r < 4; r++) {
                    const size_t row = m0 + wr * 64 + mf * 16 + r4 + r;
                    float v = acc[mf][nf][r];
                    obf[row * 3072 + colb + la15] = f2bf(feat ? elu1(v) : v);
                }
            }
    } else {
#pragma unroll
        for (int mf = 0; mf < 4; mf++)
#pragma unroll
            for (int nf = 0; nf < 4; nf++) {
                const size_t col = n0 + wc * 64 + nf * 16 + la15;
                const float bo = bout[col];
#pragma unroll
                for (int r = 0; r < 4; r++) {
                    const size_t row = m0 + wr * 64 + mf * 16 + r4 + r;
                    of[row * 1024 + col] = acc[mf][nf][r] + bo;
                }
            }
    }
}

// =====================================================================
// kv[b][h][f][d] += sum_n k_feat[n][d] * v[n][f]  (TRANSPOSED: kvT[f][d])
// ksum[b][h][d]  += sum_n k_feat[n][d]
// grid (16 heads, 8 n-splits of 1024, 4 batches) = 512 blocks.
// Staging: register 4x4 transpose + ds_write_b64.
// =====================================================================
#define KST 136
__global__ __launch_bounds__(256) void k_kv(
    const ushort_t* __restrict__ qkv, float* __restrict__ kv, float* __restrict__ ksum)
{
    __shared__ ushort_t kT[64 * KST];
    __shared__ ushort_t vT[64 * KST];
    __shared__ float ksl[64];
    const int t = threadIdx.x, l = t & 63, w = t >> 6;
    const int wr = w >> 1, wc = w & 1;
    const int h = blockIdx.x;
    const int b = blockIdx.z;
    const ushort_t* qkvb = qkv + (size_t)b * 8192 * 3072;
    float* kvh = kv + ((size_t)b * 16 + h) * 4096;
    float* ksh = ksum + (size_t)b * 1024 + h * 64;
    const int n00 = blockIdx.y * 1024;
    const f32x4 z = {0.f, 0.f, 0.f, 0.f};
    f32x4 acc[2][2] = {{z, z}, {z, z}};
    float ksloc[4] = {0.f, 0.f, 0.f, 0.f};
    const int sd0 = (t & 15) * 4;
    const int tg  = t >> 4;               // 0..15
    if (t < 64) ksl[t] = 0.f;

    for (int c = 0; c < 8; c++) {
        __syncthreads();
        const int n0 = n00 + c * 128;
#pragma unroll
        for (int jj = 0; jj < 2; jj++) {
            const int nb = tg * 8 + jj * 4;          // 4-row group
            ushort4 kw[4], vw[4];
#pragma unroll
            for (int j = 0; j < 4; j++) {
                const ushort_t* kp = qkvb + (size_t)(n0 + nb + j) * 3072 + 1024 + h * 64 + sd0;
                kw[j] = *(const ushort4*)kp;
                vw[j] = *(const ushort4*)(kp + 1024);
            }
#pragma unroll
            for (int j = 0; j < 4; j++) {
                ksloc[0] += bf2f(kw[j].x); ksloc[1] += bf2f(kw[j].y);
                ksloc[2] += bf2f(kw[j].z); ksloc[3] += bf2f(kw[j].w);
            }
            *(ushort4*)&kT[(sd0 + 0) * KST + nb] = make_ushort4(kw[0].x, kw[1].x, kw[2].x, kw[3].x);
            *(ushort4*)&kT[(sd0 + 1) * KST + nb] = make_ushort4(kw[0].y, kw[1].y, kw[2].y, kw[3].y);
            *(ushort4*)&kT[(sd0 + 2) * KST + nb] = make_ushort4(kw[0].z, kw[1].z, kw[2].z, kw[3].z);
            *(ushort4*)&kT[(sd0 + 3) * KST + nb] = make_ushort4(kw[0].w, kw[1].w, kw[2].w, kw[3].w);
            *(ushort4*)&vT[(sd0 + 0) * KST + nb] = make_ushort4(vw[0].x, vw[1].x, vw[2].x, vw[3].x);
            *(ushort4*)&vT[(sd0 + 1) * KST + nb] = make_ushort4(vw[0].y, vw[1].y, vw[2].y, vw[3].y);
            *(ushort4*)&vT[(sd0 + 2) * KST + nb] = make_ushort4(vw[0].z, vw[1].z, vw[2].z, vw[3].z);
            *(ushort4*)&vT[(sd0 + 3) * KST + nb] = make_ushort4(vw[0].w, vw[1].w, vw[2].w, vw[3].w);
        }
        __syncthreads();
#pragma unroll
        for (int kb = 0; kb < 128; kb += 32) {
            s8v af[2], bfr[2];
#pragma unroll
            for (int ma = 0; ma < 2; ma++) {
                int d = wr * 32 + ma * 16 + (l & 15);
                af[ma] = *(const s8v*)&kT[d * KST + kb + (l >> 4) * 8];
            }
#pragma unroll
            for (int fb = 0; fb < 2; fb++) {
                int f = wc * 32 + fb * 16 + (l & 15);
                bfr[fb] = *(const s8v*)&vT[f * KST + kb + (l >> 4) * 8];
            }
#pragma unroll
            for (int ma = 0; ma < 2; ma++)
#pragma unroll
                for (int fb = 0; fb < 2; fb++)
                    acc[ma][fb] = MFMA(af[ma], bfr[fb], acc[ma][fb]);
        }
    }
    atomicAdd(&ksl[sd0 + 0], ksloc[0]); atomicAdd(&ksl[sd0 + 1], ksloc[1]);
    atomicAdd(&ksl[sd0 + 2], ksloc[2]); atomicAdd(&ksl[sd0 + 3], ksloc[3]);
    __syncthreads();
    if (t < 64) atomicAdd(&ksh[t], ksl[t]);
#pragma unroll
    for (int ma = 0; ma < 2; ma++)
#pragma unroll
        for (int fb = 0; fb < 2; fb++)
#pragma unroll
            for (int r = 0; r < 4; r++) {
                int d = wr * 32 + ma * 16 + (l >> 4) * 4 + r;
                int f = wc * 32 + fb * 16 + (l & 15);
                atomicAdd(&kvh[f * 64 + d], acc[ma][fb][r]);
            }
}

// =====================================================================
// k_apply (den fused): per head h:
//   pd(row)  = sum_d q[row][d] * ksum[b][h][d]
//   attn[row][h*64+f] = (sum_d q kvT) / (pd + eps)
// grid (32768/32, 2), 256 thr / 4 waves; wave = 32 rows x 16 f.
// Output via [32][520] LDS buffer -> coalesced dwordx4 sweep.
// =====================================================================
#define AST 72
#define OST 520
__global__ __launch_bounds__(256) void k_apply(
    const ushort_t* __restrict__ qkv, const float* __restrict__ kv,
    const float* __restrict__ ksum, ushort_t* __restrict__ attn)
{
    __shared__ ushort_t kvb[64 * AST];
    __shared__ ushort_t obuf[32 * OST];
    const int t = threadIdx.x, l = t & 63, w = t >> 6;
    const int la15 = l & 15;
    const int row0 = blockIdx.x * 32;          // global row (batches contiguous)
    const int b = row0 >> 13;
    const f32x4 z = {0.f, 0.f, 0.f, 0.f};

    for (int hh = 0; hh < 8; hh++) {
        const int h = blockIdx.y * 8 + hh;
        const float* kvh = kv + ((size_t)b * 16 + h) * 4096;
        const float* ksh = ksum + (size_t)b * 1024 + h * 64;
        __syncthreads();
        {   // stage kvT (fp32 -> bf16): thread t covers f=t>>2, d0=(t&3)*16
            const int f = t >> 2, d0 = (t & 3) * 16;
            const float* src = kvh + f * 64 + d0;
            s8v v0, v1;
#pragma unroll
            for (int j = 0; j < 8; j++) {
                v0[j] = (short)f2bf(src[j]);
                v1[j] = (short)f2bf(src[j + 8]);
            }
            *(s8v*)&kvb[f * AST + d0]     = v0;
            *(s8v*)&kvb[f * AST + d0 + 8] = v1;
        }
        __syncthreads();
        // per-lane ksum slice: elems ks*32 + (l>>4)*8 + j
        float ksv[16];
        {
            const float* kp = ksh + (l >> 4) * 8;
            *(float4*)&ksv[0]  = *(const float4*)(kp);
            *(float4*)&ksv[4]  = *(const float4*)(kp + 4);
            *(float4*)&ksv[8]  = *(const float4*)(kp + 32);
            *(float4*)&ksv[12] = *(const float4*)(kp + 36);
        }
        f32x4 acc[2] = {z, z};
        float pd[2] = {0.f, 0.f};
#pragma unroll
        for (int ks = 0; ks < 2; ks++) {
            const int f = w * 16 + la15;
            s8v bfr = *(const s8v*)&kvb[f * AST + ks * 32 + (l >> 4) * 8];
#pragma unroll
            for (int ma = 0; ma < 2; ma++) {
                int row = row0 + ma * 16 + la15;
                s8v afr = *(const s8v*)(qkv + (size_t)row * 3072 + h * 64 + ks * 32 + (l >> 4) * 8);
#pragma unroll
                for (int j = 0; j < 8; j++)
                    pd[ma] += bf2f((ushort_t)afr[j]) * ksv[ks * 8 + j];
                acc[ma] = MFMA(afr, bfr, acc[ma]);
            }
        }
        // reduce q.ksum across the 4 lane-groups covering a row
#pragma unroll
        for (int ma = 0; ma < 2; ma++) {
            pd[ma] += __shfl_xor(pd[ma], 16, 64);
            pd[ma] += __shfl_xor(pd[ma], 32, 64);
        }
#pragma unroll
        for (int ma = 0; ma < 2; ma++)
#pragma unroll
            for (int r = 0; r < 4; r++) {
                int lrow = (l >> 4) * 4 + r;                 // 0..15
                float dot = __shfl(pd[ma], lrow, 64);        // dot for row0+ma*16+lrow
                float dv = 1.f / (dot + 1e-6f);
                int orow = ma * 16 + lrow;                   // 0..31
                int ocol = hh * 64 + w * 16 + la15;          // 0..511
                obuf[orow * OST + ocol] = f2bf(acc[ma][r] * dv);
            }
    }
    __syncthreads();
    // coalesced store: 32 rows x 512 cols; thread t -> row t>>3,
    // cols (t&7)*8 + i*64 (lanes 0-7 contiguous 128B per instr)
    {
        const int row = t >> 3;
        const int c0  = (t & 7) * 8;
        ushort_t* dst = attn + (size_t)(row0 + row) * 1024 + blockIdx.y * 512;
#pragma unroll
        for (int i = 0; i < 8; i++) {
            const int col = c0 + i * 64;
            *(uint4*)(dst + col) = *(const uint4*)&obuf[row * OST + col];
        }
    }
}

// =====================================================================
// workspace layout (bytes), total ~348 MB of 512 MiB:
//  0          WqkvT  [3072][1024] bf16   6291456
//  6291456    WoutT  [1024][1024] bf16   2097152
//  8388608    kv     [4][16][64][64] f32 4194304   (kvT[f][d], zeroed)
//  12582912   ksum   [4][16][64] f32     16384     (zeroed)
//  12599296   xb     [32768][1024] bf16  67108864
//  79708160   qkv    [32768][3072] bf16  201326592
//  281034752  attn   [32768][1024] bf16  67108864
// =====================================================================
extern "C" void kernel_launch(void* const* d_in, const int* in_sizes, int n_in,
                              void* d_out, int out_size, void* d_ws, size_t ws_size,
                              hipStream_t stream) {
    const float* x    = (const float*)d_in[0];
    const float* Wqkv = (const float*)d_in[1];
    const float* Wout = (const float*)d_in[2];
    const float* bout = (const float*)d_in[3];
    float* out = (float*)d_out;
    char* ws = (char*)d_ws;

    ushort_t* WqkvT = (ushort_t*)(ws + 0);
    ushort_t* WoutT = (ushort_t*)(ws + 6291456);
    float*    kv    = (float*)(ws + 8388608);
    float*    ksum  = (float*)(ws + 12582912);
    ushort_t* xb    = (ushort_t*)(ws + 12599296);
    ushort_t* qkv   = (ushort_t*)(ws + 79708160);
    ushort_t* attn  = (ushort_t*)(ws + 281034752);

    k_prep<<<20512, 256, 0, stream>>>(x, Wqkv, Wout, xb, WqkvT, WoutT, kv);

    k_gemm<0><<<6144, 256, 0, stream>>>(xb, WqkvT, qkv, nullptr, nullptr);
    k_kv<<<dim3(16, 8, 4), 256, 0, stream>>>(qkv, kv, ksum);
    k_apply<<<dim3(1024, 2), 256, 0, stream>>>(qkv, kv, ksum, attn);
    k_gemm<1><<<2048, 256, 0, stream>>>(attn, WoutT, nullptr, bout, out);
}

// Round 18
// 479.081 us; speedup vs baseline: 1.0040x; 1.0040x over previous
//
#include <hip/hip_runtime.h>
#include <hip/hip_bf16.h>
#include <math.h>

// ---------------- problem constants ----------------
// x[4][8192][1024] fp32; Wqkv[1024][3072]; Wout[1024][1024]; bout[1024]
// ALL 4 batches in one pass (ws 512 MiB). ROWS = 32768.

typedef unsigned short ushort_t;
typedef __attribute__((ext_vector_type(8))) short s8v;   // 8 bf16 (4 VGPRs) MFMA A/B frag
typedef __attribute__((ext_vector_type(4))) float f32x4; // MFMA C/D frag

#define MFMA(a,b,c) __builtin_amdgcn_mfma_f32_16x16x32_bf16((a),(b),(c),0,0,0)

typedef __attribute__((address_space(3))) unsigned int as3_u32;
typedef __attribute__((address_space(1))) const unsigned int as1_u32c;

// async global -> LDS, 16B per lane. LDS dest = wave-uniform base + lane*16.
__device__ __forceinline__ void g2l16(const void* g, void* l) {
    __builtin_amdgcn_global_load_lds((as1_u32c*)g, (as3_u32*)l, 16, 0, 0);
}

__device__ __forceinline__ float bf2f(ushort_t u) {
    union { float f; unsigned v; } x; x.v = ((unsigned)u) << 16; return x.f;
}
__device__ __forceinline__ ushort_t f2bf(float f) {
    union { float f; unsigned v; } x; x.f = f;
    unsigned r = x.v + 0x7fffu + ((x.v >> 16) & 1u);   // RNE
    return (ushort_t)(r >> 16);
}
__device__ __forceinline__ float elu1(float t) { return t > 0.0f ? t + 1.0f : expf(t); }

// =====================================================================
// k_prep: ONE kernel for all preprocessing. Block-ID ranges:
//  [0,3072)        : WqkvT transpose tiles (32 k-tiles x 96 n-tiles)
//  [3072,4096)     : WoutT transpose tiles (32 x 32)
//  [4096,20480)    : x fp32 -> bf16 cast (16384 blocks x 2048 elems)
//  [20480,20512)   : zero kv+ksum (grid-stride float4)
// =====================================================================
__global__ __launch_bounds__(256) void k_prep(
    const float* __restrict__ x, const float* __restrict__ Wqkv,
    const float* __restrict__ Wout, ushort_t* __restrict__ xb,
    ushort_t* __restrict__ WqkvT, ushort_t* __restrict__ WoutT,
    float* __restrict__ zeroreg)
{
    const int bid = blockIdx.x, t = threadIdx.x;
    if (bid < 4096) {
        const float* W; ushort_t* WT; int K, N, idx;
        if (bid < 3072) { W = Wqkv; WT = WqkvT; K = 1024; N = 3072; idx = bid; }
        else            { W = Wout; WT = WoutT; K = 1024; N = 1024; idx = bid - 3072; }
        const int k0 = (idx & 31) * 32, n0 = (idx >> 5) * 32;
        __shared__ float s[32][33];
        const int kr = t >> 3, n4 = (t & 7) * 4;
        float4 v = *(const float4*)(W + (size_t)(k0 + kr) * N + n0 + n4);
        s[kr][n4 + 0] = v.x; s[kr][n4 + 1] = v.y; s[kr][n4 + 2] = v.z; s[kr][n4 + 3] = v.w;
        __syncthreads();
        const int nr = kr, k4 = n4;
        unsigned lo = (unsigned)f2bf(s[k4 + 0][nr]) | ((unsigned)f2bf(s[k4 + 1][nr]) << 16);
        unsigned hi = (unsigned)f2bf(s[k4 + 2][nr]) | ((unsigned)f2bf(s[k4 + 3][nr]) << 16);
        *(uint2*)(WT + (size_t)(n0 + nr) * K + k0 + k4) = make_uint2(lo, hi);
    } else if (bid < 20480) {
        const size_t i = (size_t)(bid - 4096) * 256 + t;     // < 4194304
        const float4* p = (const float4*)x;
        float4 a = p[i * 2], b = p[i * 2 + 1];
        uint4 o;
        o.x = (unsigned)f2bf(a.x) | ((unsigned)f2bf(a.y) << 16);
        o.y = (unsigned)f2bf(a.z) | ((unsigned)f2bf(a.w) << 16);
        o.z = (unsigned)f2bf(b.x) | ((unsigned)f2bf(b.y) << 16);
        o.w = (unsigned)f2bf(b.z) | ((unsigned)f2bf(b.w) << 16);
        *(uint4*)(xb + i * 8) = o;
    } else {
        float4* dst = (float4*)zeroreg;
        const float4 z4 = {0.f, 0.f, 0.f, 0.f};
        for (int i = (bid - 20480) * 256 + t; i < 263168; i += 8192)
            dst[i] = z4;
    }
}

// =====================================================================
// GEMM1 (qkv): m97 structure at 128x128, measured 227us / MfmaUtil 42 /
// occupancy 39% (R17). BM=BN=128, BK=64, 4 waves (2x2), 256 thr,
// single-buffered 32 KB LDS -> ~3 blocks/CU co-resident (m114
// inter-block overlap). Per K-tile: stage; vmcnt(0); barrier; 2
// k-halves x {8 ds_read_b128 + 16 MFMA}; barrier.
// XOR swizzle (conflicts=0): stage-source slot (l&7)^lr; read elem
// ((l>>4)^(l&7))*8, ^32 for kh1. XCD-chunked bijective grid swizzle.
// Epilogue: elu1 on cols<2048 -> qkv bf16 [M][3072].
// =====================================================================
__global__ __launch_bounds__(256, 4) void k_gemm1(
    const ushort_t* __restrict__ A, const ushort_t* __restrict__ B,
    ushort_t* __restrict__ obf)
{
    constexpr int ASZ = 128 * 64;         // 8192 elems (16 KB) per matrix
    constexpr int NBN = 24;               // N blocks (3072)
    constexpr int CH  = (256 * NBN) / 8;  // wgs per XCD chunk
    __shared__ ushort_t As[ASZ];
    __shared__ ushort_t Bs[ASZ];

    const int t = threadIdx.x, l = t & 63, w = t >> 6;   // 4 waves
    const int wr = w >> 1, wc = w & 1;                   // 2M x 2N
    const int orig = blockIdx.x;
    const int wg   = (orig & 7) * CH + (orig >> 3);
    const size_t m0 = (size_t)(wg / NBN) * 128;
    const size_t n0 = (size_t)(wg % NBN) * 128;

    f32x4 acc[4][4];
    const f32x4 z = {0.f, 0.f, 0.f, 0.f};
#pragma unroll
    for (int i = 0; i < 4; i++)
#pragma unroll
        for (int j = 0; j < 4; j++) acc[i][j] = z;

    const int lr  = l >> 3;
    const int lco = ((l & 7) ^ lr) << 3;
    const ushort_t* gA = A + (m0 + (size_t)(32 * w) + lr) * 1024 + lco;
    const ushort_t* gB = B + (n0 + (size_t)(32 * w) + lr) * 1024 + lco;
    const int la15 = l & 15;
    const int exo  = (((l >> 4) ^ (l & 7)) << 3);

    for (int T = 0; T < 16; ++T) {
        const size_t k0 = (size_t)T * 64;
#pragma unroll
        for (int i = 0; i < 4; i++) {
            g2l16(gA + (size_t)(8 * i) * 1024 + k0, &As[(w * 4 + i) * 512]);
            g2l16(gB + (size_t)(8 * i) * 1024 + k0, &Bs[(w * 4 + i) * 512]);
        }
        asm volatile("s_waitcnt vmcnt(0)" ::: "memory");
        __builtin_amdgcn_sched_barrier(0);
        __builtin_amdgcn_s_barrier();
        __builtin_amdgcn_sched_barrier(0);

#pragma unroll
        for (int kh = 0; kh < 2; kh++) {
            const int eo = (kh << 5) ^ exo;
            s8v af[4], bf[4];
#pragma unroll
            for (int nf = 0; nf < 4; nf++)
                bf[nf] = *(const s8v*)&Bs[(wc * 64 + nf * 16 + la15) * 64 + eo];
#pragma unroll
            for (int mf = 0; mf < 4; mf++)
                af[mf] = *(const s8v*)&As[(wr * 64 + mf * 16 + la15) * 64 + eo];
            __builtin_amdgcn_s_setprio(1);
#pragma unroll
            for (int mf = 0; mf < 4; mf++)
#pragma unroll
                for (int nf = 0; nf < 4; nf++)
                    acc[mf][nf] = MFMA(af[mf], bf[nf], acc[mf][nf]);
            __builtin_amdgcn_s_setprio(0);
        }
        __builtin_amdgcn_sched_barrier(0);
        __builtin_amdgcn_s_barrier();     // reads done before next stage
        __builtin_amdgcn_sched_barrier(0);
    }

    const int r4 = (l >> 4) * 4;
#pragma unroll
    for (int mf = 0; mf < 4; mf++)
#pragma unroll
        for (int nf = 0; nf < 4; nf++) {
            const size_t colb = n0 + wc * 64 + nf * 16;
            const bool feat = colb < 2048;
#pragma unroll
            for (int r = 0; r < 4; r++) {
                const size_t row = m0 + wr * 64 + mf * 16 + r4 + r;
                float v = acc[mf][nf][r];
                obf[row * 3072 + colb + la15] = f2bf(feat ? elu1(v) : v);
            }
        }
}

// =====================================================================
// GEMM2 (out): R16 256x256 double-buffered core (measured ~82-86us for
// this shape; 128x128 regressed it to ~103 via 2x A-refetch -- N=1024
// is the ratio-poor GEMM). BM=BN=256, BK=64, 8 waves, 512 thr, 128 KB
// LDS, drain-0 schedule + T1 swizzle. Epilogue +bout -> fp32.
// =====================================================================
__global__ __launch_bounds__(512, 2) void k_gemm2(
    const ushort_t* __restrict__ A, const ushort_t* __restrict__ B,
    const float* __restrict__ bout, float* __restrict__ of)
{
    constexpr int ASZ  = 256 * 64;        // 16384 elems (32 KB)
    constexpr int BUFS = 2 * ASZ;         // A+B per buffer (64 KB)
    constexpr int NBN  = 4;               // N blocks (1024)
    constexpr int CH   = (128 * NBN) / 8; // wgs per XCD chunk
    __shared__ ushort_t lds[2 * BUFS];    // 128 KB

    const int t = threadIdx.x, l = t & 63, w = t >> 6;   // 8 waves
    const int wr = w >> 2, wc = w & 3;                   // 2M x 4N
    const int orig = blockIdx.x;
    const int wg   = (orig & 7) * CH + (orig >> 3);
    const size_t m0 = (size_t)(wg / NBN) * 256;
    const size_t n0 = (size_t)(wg % NBN) * 256;

    f32x4 acc[8][4];
    const f32x4 z = {0.f, 0.f, 0.f, 0.f};
#pragma unroll
    for (int i = 0; i < 8; i++)
#pragma unroll
        for (int j = 0; j < 4; j++) acc[i][j] = z;

    const int lr  = l >> 3;
    const int lco = ((l & 7) ^ lr) << 3;
    const ushort_t* gA = A + (m0 + (size_t)(32 * w) + lr) * 1024 + lco;
    const ushort_t* gB = B + (n0 + (size_t)(32 * w) + lr) * 1024 + lco;
    const int la15 = l & 15;
    const int exo  = (((l >> 4) ^ (l & 7)) << 3);

    // ---- prologue: stage tile 0 -> buf 0
#pragma unroll
    for (int i = 0; i < 4; i++)
        g2l16(gA + (size_t)(8 * i) * 1024, &lds[(w * 4 + i) * 512]);
#pragma unroll
    for (int i = 0; i < 4; i++)
        g2l16(gB + (size_t)(8 * i) * 1024, &lds[ASZ + (w * 4 + i) * 512]);
    asm volatile("s_waitcnt vmcnt(0)" ::: "memory");
    __builtin_amdgcn_sched_barrier(0);
    __builtin_amdgcn_s_barrier();
    __builtin_amdgcn_sched_barrier(0);

    for (int T = 0; T < 16; ++T) {
        const int base  = (T & 1) * BUFS;
        const int nbase = BUFS - base;

        if (T < 15) {
            const size_t k1 = (size_t)(T + 1) * 64;
#pragma unroll
            for (int i = 0; i < 4; i++)
                g2l16(gA + (size_t)(8 * i) * 1024 + k1, &lds[nbase + (w * 4 + i) * 512]);
#pragma unroll
            for (int i = 0; i < 4; i++)
                g2l16(gB + (size_t)(8 * i) * 1024 + k1, &lds[nbase + ASZ + (w * 4 + i) * 512]);
        }

        s8v af[8], bf[4];
#pragma unroll
        for (int nf = 0; nf < 4; nf++)
            bf[nf] = *(const s8v*)&lds[base + ASZ + (wc * 64 + nf * 16 + la15) * 64 + exo];
#pragma unroll
        for (int mf = 0; mf < 8; mf++)
            af[mf] = *(const s8v*)&lds[base + (wr * 128 + mf * 16 + la15) * 64 + exo];
        __builtin_amdgcn_s_setprio(1);
#pragma unroll
        for (int mf = 0; mf < 8; mf++)
#pragma unroll
            for (int nf = 0; nf < 4; nf++)
                acc[mf][nf] = MFMA(af[mf], bf[nf], acc[mf][nf]);
        __builtin_amdgcn_s_setprio(0);
#pragma unroll
        for (int nf = 0; nf < 4; nf++)
            bf[nf] = *(const s8v*)&lds[base + ASZ + (wc * 64 + nf * 16 + la15) * 64 + (32 ^ exo)];
#pragma unroll
        for (int mf = 0; mf < 8; mf++)
            af[mf] = *(const s8v*)&lds[base + (wr * 128 + mf * 16 + la15) * 64 + (32 ^ exo)];
        __builtin_amdgcn_s_setprio(1);
#pragma unroll
        for (int mf = 0; mf < 8; mf++)
#pragma unroll
            for (int nf = 0; nf < 4; nf++)
                acc[mf][nf] = MFMA(af[mf], bf[nf], acc[mf][nf]);
        __builtin_amdgcn_s_setprio(0);

        if (T < 15) {
            __builtin_amdgcn_sched_barrier(0);
            asm volatile("s_waitcnt vmcnt(0)" ::: "memory");
            __builtin_amdgcn_sched_barrier(0);
            __builtin_amdgcn_s_barrier();
            __builtin_amdgcn_sched_barrier(0);
        }
    }

    const int r4 = (l >> 4) * 4;
#pragma unroll
    for (int mf = 0; mf < 8; mf++)
#pragma unroll
        for (int nf = 0; nf < 4; nf++) {
            const size_t col = n0 + wc * 64 + nf * 16 + la15;
            const float bo = bout[col];
#pragma unroll
            for (int r = 0; r < 4; r++) {
                const size_t row = m0 + wr * 128 + mf * 16 + r4 + r;
                of[row * 1024 + col] = acc[mf][nf][r] + bo;
            }
        }
}

// =====================================================================
// kv[b][h][f][d] += sum_n k_feat[n][d] * v[n][f]  (TRANSPOSED: kvT[f][d])
// ksum[b][h][d]  += sum_n k_feat[n][d]
// grid (16 heads, 8 n-splits of 1024, 4 batches) = 512 blocks.
// Staging: register 4x4 transpose + ds_write_b64.
// =====================================================================
#define KST 136
__global__ __launch_bounds__(256) void k_kv(
    const ushort_t* __restrict__ qkv, float* __restrict__ kv, float* __restrict__ ksum)
{
    __shared__ ushort_t kT[64 * KST];
    __shared__ ushort_t vT[64 * KST];
    __shared__ float ksl[64];
    const int t = threadIdx.x, l = t & 63, w = t >> 6;
    const int wr = w >> 1, wc = w & 1;
    const int h = blockIdx.x;
    const int b = blockIdx.z;
    const ushort_t* qkvb = qkv + (size_t)b * 8192 * 3072;
    float* kvh = kv + ((size_t)b * 16 + h) * 4096;
    float* ksh = ksum + (size_t)b * 1024 + h * 64;
    const int n00 = blockIdx.y * 1024;
    const f32x4 z = {0.f, 0.f, 0.f, 0.f};
    f32x4 acc[2][2] = {{z, z}, {z, z}};
    float ksloc[4] = {0.f, 0.f, 0.f, 0.f};
    const int sd0 = (t & 15) * 4;
    const int tg  = t >> 4;               // 0..15
    if (t < 64) ksl[t] = 0.f;

    for (int c = 0; c < 8; c++) {
        __syncthreads();
        const int n0 = n00 + c * 128;
#pragma unroll
        for (int jj = 0; jj < 2; jj++) {
            const int nb = tg * 8 + jj * 4;          // 4-row group
            ushort4 kw[4], vw[4];
#pragma unroll
            for (int j = 0; j < 4; j++) {
                const ushort_t* kp = qkvb + (size_t)(n0 + nb + j) * 3072 + 1024 + h * 64 + sd0;
                kw[j] = *(const ushort4*)kp;
                vw[j] = *(const ushort4*)(kp + 1024);
            }
#pragma unroll
            for (int j = 0; j < 4; j++) {
                ksloc[0] += bf2f(kw[j].x); ksloc[1] += bf2f(kw[j].y);
                ksloc[2] += bf2f(kw[j].z); ksloc[3] += bf2f(kw[j].w);
            }
            *(ushort4*)&kT[(sd0 + 0) * KST + nb] = make_ushort4(kw[0].x, kw[1].x, kw[2].x, kw[3].x);
            *(ushort4*)&kT[(sd0 + 1) * KST + nb] = make_ushort4(kw[0].y, kw[1].y, kw[2].y, kw[3].y);
            *(ushort4*)&kT[(sd0 + 2) * KST + nb] = make_ushort4(kw[0].z, kw[1].z, kw[2].z, kw[3].z);
            *(ushort4*)&kT[(sd0 + 3) * KST + nb] = make_ushort4(kw[0].w, kw[1].w, kw[2].w, kw[3].w);
            *(ushort4*)&vT[(sd0 + 0) * KST + nb] = make_ushort4(vw[0].x, vw[1].x, vw[2].x, vw[3].x);
            *(ushort4*)&vT[(sd0 + 1) * KST + nb] = make_ushort4(vw[0].y, vw[1].y, vw[2].y, vw[3].y);
            *(ushort4*)&vT[(sd0 + 2) * KST + nb] = make_ushort4(vw[0].z, vw[1].z, vw[2].z, vw[3].z);
            *(ushort4*)&vT[(sd0 + 3) * KST + nb] = make_ushort4(vw[0].w, vw[1].w, vw[2].w, vw[3].w);
        }
        __syncthreads();
#pragma unroll
        for (int kb = 0; kb < 128; kb += 32) {
            s8v af[2], bfr[2];
#pragma unroll
            for (int ma = 0; ma < 2; ma++) {
                int d = wr * 32 + ma * 16 + (l & 15);
                af[ma] = *(const s8v*)&kT[d * KST + kb + (l >> 4) * 8];
            }
#pragma unroll
            for (int fb = 0; fb < 2; fb++) {
                int f = wc * 32 + fb * 16 + (l & 15);
                bfr[fb] = *(const s8v*)&vT[f * KST + kb + (l >> 4) * 8];
            }
#pragma unroll
            for (int ma = 0; ma < 2; ma++)
#pragma unroll
                for (int fb = 0; fb < 2; fb++)
                    acc[ma][fb] = MFMA(af[ma], bfr[fb], acc[ma][fb]);
        }
    }
    atomicAdd(&ksl[sd0 + 0], ksloc[0]); atomicAdd(&ksl[sd0 + 1], ksloc[1]);
    atomicAdd(&ksl[sd0 + 2], ksloc[2]); atomicAdd(&ksl[sd0 + 3], ksloc[3]);
    __syncthreads();
    if (t < 64) atomicAdd(&ksh[t], ksl[t]);
#pragma unroll
    for (int ma = 0; ma < 2; ma++)
#pragma unroll
        for (int fb = 0; fb < 2; fb++)
#pragma unroll
            for (int r = 0; r < 4; r++) {
                int d = wr * 32 + ma * 16 + (l >> 4) * 4 + r;
                int f = wc * 32 + fb * 16 + (l & 15);
                atomicAdd(&kvh[f * 64 + d], acc[ma][fb][r]);
            }
}

// =====================================================================
// k_apply (den fused): per head h:
//   pd(row)  = sum_d q[row][d] * ksum[b][h][d]
//   attn[row][h*64+f] = (sum_d q kvT) / (pd + eps)
// grid (32768/32, 2), 256 thr / 4 waves; wave = 32 rows x 16 f.
// Output via [32][520] LDS buffer -> coalesced dwordx4 sweep.
// =====================================================================
#define AST 72
#define OST 520
__global__ __launch_bounds__(256) void k_apply(
    const ushort_t* __restrict__ qkv, const float* __restrict__ kv,
    const float* __restrict__ ksum, ushort_t* __restrict__ attn)
{
    __shared__ ushort_t kvb[64 * AST];
    __shared__ ushort_t obuf[32 * OST];
    const int t = threadIdx.x, l = t & 63, w = t >> 6;
    const int la15 = l & 15;
    const int row0 = blockIdx.x * 32;          // global row (batches contiguous)
    const int b = row0 >> 13;
    const f32x4 z = {0.f, 0.f, 0.f, 0.f};

    for (int hh = 0; hh < 8; hh++) {
        const int h = blockIdx.y * 8 + hh;
        const float* kvh = kv + ((size_t)b * 16 + h) * 4096;
        const float* ksh = ksum + (size_t)b * 1024 + h * 64;
        __syncthreads();
        {   // stage kvT (fp32 -> bf16): thread t covers f=t>>2, d0=(t&3)*16
            const int f = t >> 2, d0 = (t & 3) * 16;
            const float* src = kvh + f * 64 + d0;
            s8v v0, v1;
#pragma unroll
            for (int j = 0; j < 8; j++) {
                v0[j] = (short)f2bf(src[j]);
                v1[j] = (short)f2bf(src[j + 8]);
            }
            *(s8v*)&kvb[f * AST + d0]     = v0;
            *(s8v*)&kvb[f * AST + d0 + 8] = v1;
        }
        __syncthreads();
        // per-lane ksum slice: elems ks*32 + (l>>4)*8 + j
        float ksv[16];
        {
            const float* kp = ksh + (l >> 4) * 8;
            *(float4*)&ksv[0]  = *(const float4*)(kp);
            *(float4*)&ksv[4]  = *(const float4*)(kp + 4);
            *(float4*)&ksv[8]  = *(const float4*)(kp + 32);
            *(float4*)&ksv[12] = *(const float4*)(kp + 36);
        }
        f32x4 acc[2] = {z, z};
        float pd[2] = {0.f, 0.f};
#pragma unroll
        for (int ks = 0; ks < 2; ks++) {
            const int f = w * 16 + la15;
            s8v bfr = *(const s8v*)&kvb[f * AST + ks * 32 + (l >> 4) * 8];
#pragma unroll
            for (int ma = 0; ma < 2; ma++) {
                int row = row0 + ma * 16 + la15;
                s8v afr = *(const s8v*)(qkv + (size_t)row * 3072 + h * 64 + ks * 32 + (l >> 4) * 8);
#pragma unroll
                for (int j = 0; j < 8; j++)
                    pd[ma] += bf2f((ushort_t)afr[j]) * ksv[ks * 8 + j];
                acc[ma] = MFMA(afr, bfr, acc[ma]);
            }
        }
        // reduce q.ksum across the 4 lane-groups covering a row
#pragma unroll
        for (int ma = 0; ma < 2; ma++) {
            pd[ma] += __shfl_xor(pd[ma], 16, 64);
            pd[ma] += __shfl_xor(pd[ma], 32, 64);
        }
#pragma unroll
        for (int ma = 0; ma < 2; ma++)
#pragma unroll
            for (int r = 0; r < 4; r++) {
                int lrow = (l >> 4) * 4 + r;                 // 0..15
                float dot = __shfl(pd[ma], lrow, 64);        // dot for row0+ma*16+lrow
                float dv = 1.f / (dot + 1e-6f);
                int orow = ma * 16 + lrow;                   // 0..31
                int ocol = hh * 64 + w * 16 + la15;          // 0..511
                obuf[orow * OST + ocol] = f2bf(acc[ma][r] * dv);
            }
    }
    __syncthreads();
    // coalesced store: 32 rows x 512 cols; thread t -> row t>>3,
    // cols (t&7)*8 + i*64 (lanes 0-7 contiguous 128B per instr)
    {
        const int row = t >> 3;
        const int c0  = (t & 7) * 8;
        ushort_t* dst = attn + (size_t)(row0 + row) * 1024 + blockIdx.y * 512;
#pragma unroll
        for (int i = 0; i < 8; i++) {
            const int col = c0 + i * 64;
            *(uint4*)(dst + col) = *(const uint4*)&obuf[row * OST + col];
        }
    }
}

// =====================================================================
// workspace layout (bytes), total ~348 MB of 512 MiB:
//  0          WqkvT  [3072][1024] bf16   6291456
//  6291456    WoutT  [1024][1024] bf16   2097152
//  8388608    kv     [4][16][64][64] f32 4194304   (kvT[f][d], zeroed)
//  12582912   ksum   [4][16][64] f32     16384     (zeroed)
//  12599296   xb     [32768][1024] bf16  67108864
//  79708160   qkv    [32768][3072] bf16  201326592
//  281034752  attn   [32768][1024] bf16  67108864
// =====================================================================
extern "C" void kernel_launch(void* const* d_in, const int* in_sizes, int n_in,
                              void* d_out, int out_size, void* d_ws, size_t ws_size,
                              hipStream_t stream) {
    const float* x    = (const float*)d_in[0];
    const float* Wqkv = (const float*)d_in[1];
    const float* Wout = (const float*)d_in[2];
    const float* bout = (const float*)d_in[3];
    float* out = (float*)d_out;
    char* ws = (char*)d_ws;

    ushort_t* WqkvT = (ushort_t*)(ws + 0);
    ushort_t* WoutT = (ushort_t*)(ws + 6291456);
    float*    kv    = (float*)(ws + 8388608);
    float*    ksum  = (float*)(ws + 12582912);
    ushort_t* xb    = (ushort_t*)(ws + 12599296);
    ushort_t* qkv   = (ushort_t*)(ws + 79708160);
    ushort_t* attn  = (ushort_t*)(ws + 281034752);

    k_prep<<<20512, 256, 0, stream>>>(x, Wqkv, Wout, xb, WqkvT, WoutT, kv);

    k_gemm1<<<6144, 256, 0, stream>>>(xb, WqkvT, qkv);
    k_kv<<<dim3(16, 8, 4), 256, 0, stream>>>(qkv, kv, ksum);
    k_apply<<<dim3(1024, 2), 256, 0, stream>>>(qkv, kv, ksum, attn);
    k_gemm2<<<512, 512, 0, stream>>>(attn, WoutT, bout, out);
}